// Round 2
// baseline (1009.672 us; speedup 1.0000x reference)
//
#include <hip/hip_runtime.h>
#include <hip/hip_bf16.h>

// ---------------------------------------------------------------------------
// Problem geometry (fixed): B=8, C=128, H=W=128, hw=16384, num_head=8
// Pipeline (per batch-chunk of NB batches, NB adaptive to ws_size):
//  K1: t = pos_w (1x1 conv, 128->384) + pos_b            [SGEMM 384xNB*hw x128]
//  K2a: conv3(t) grouped (192 groups of 2) -> q(128ch, in d_out), k(0..63)
//  K2b: conv5(t) grouped -> k(64..127), v(128ch)
//  K3: Gram S[16x16], |q|^2, |k|^2 per (b,h)  (atomic partials)
//  K4: A = softmax(S/(nq nk) * temp); fold into proj: Wall[b] = [proj_L@A | proj_R]
//  K5a: d3(x), d5(x) grouped convs -> vy rows 128..255
//  K5b: out = Wall[b] @ [v; d3x; d5x]                    [SGEMM 128xhw x256]
// ---------------------------------------------------------------------------

#define HW 16384
#define HH 128
#define WW 128

__global__ void zerok(float* p, int n) {
    int i = blockIdx.x * 256 + threadIdx.x;
    if (i < n) p[i] = 0.f;
}

// ---------------- tiled f32 GEMM: C[m][n] = sum_k A[m][k]*B[k][n] (+bias[m])
__global__ __launch_bounds__(256) void sgemm_bias(
    const float* __restrict__ A, const float* __restrict__ B,
    float* __restrict__ C, const float* __restrict__ bias,
    int M, int K, int ldb, int ldc,
    long astride, long bstride, long cstride)
{
    int b = blockIdx.z;
    A += (long)b * astride;
    B += (long)b * bstride;
    C += (long)b * cstride;
    int m0 = blockIdx.y * 64, n0 = blockIdx.x * 64;
    __shared__ float As[16][64];
    __shared__ float Bs[16][64];
    int tid = threadIdx.x;
    int tx = tid & 15, ty = tid >> 4;
    float acc[4][4] = {};
    for (int k0 = 0; k0 < K; k0 += 16) {
        {   // A tile: As[kk][mm] = A[(m0+mm)*K + k0+kk]
            int mm = tid & 63;
            int kg = tid >> 6;       // 0..3
            #pragma unroll
            for (int j = 0; j < 4; ++j) {
                int kk = kg * 4 + j;
                As[kk][mm] = A[(long)(m0 + mm) * K + k0 + kk];
            }
        }
        {   // B tile: Bs[kk][nn] = B[(k0+kk)*ldb + n0+nn]
            int nn = tid & 63;
            int kg = tid >> 6;
            #pragma unroll
            for (int j = 0; j < 4; ++j) {
                int kk = kg + j * 4;
                Bs[kk][nn] = B[(long)(k0 + kk) * ldb + n0 + nn];
            }
        }
        __syncthreads();
        #pragma unroll
        for (int kk = 0; kk < 16; ++kk) {
            float a[4], bb[4];
            #pragma unroll
            for (int i = 0; i < 4; ++i) a[i] = As[kk][ty * 4 + i];
            #pragma unroll
            for (int j = 0; j < 4; ++j) bb[j] = Bs[kk][tx * 4 + j];
            #pragma unroll
            for (int i = 0; i < 4; ++i)
                #pragma unroll
                for (int j = 0; j < 4; ++j)
                    acc[i][j] += a[i] * bb[j];
        }
        __syncthreads();
    }
    #pragma unroll
    for (int i = 0; i < 4; ++i) {
        int m = m0 + ty * 4 + i;
        float bv = bias ? bias[m] : 0.f;
        #pragma unroll
        for (int j = 0; j < 4; ++j)
            C[(long)m * ldc + n0 + tx * 4 + j] = acc[i][j] + bv;
    }
}

// ---------------- grouped conv, 2 input channels per group, KSxKS, pad KS/2.
template<int KS>
__global__ __launch_bounds__(256) void gconv(
    const float* __restrict__ src, int srcC,
    const float* __restrict__ w,    // [G][2][KS][KS]
    const float* __restrict__ bias, // [G]
    int split,
    float* __restrict__ p0, long b0,
    float* __restrict__ p1, long b1)
{
    constexpr int PAD = KS / 2;
    constexpr int RW = 2 + 2 * PAD;      // staged rows for 2 output rows
    constexpr int W2 = WW + 2 * PAD;
    int g = blockIdx.y, b = blockIdx.z, y0 = blockIdx.x * 2;
    __shared__ float tile[2][RW][W2];
    const float* s = src + ((long)b * srcC + 2 * g) * HW;
    int tid = threadIdx.x;
    const int total = 2 * RW * W2;
    for (int idx = tid; idx < total; idx += 256) {
        int c = idx / (RW * W2);
        int rem = idx % (RW * W2);
        int r = rem / W2, ci = rem % W2;
        int col = ci - PAD;
        int row = y0 - PAD + r;
        float v = 0.f;
        if (row >= 0 && row < HH && col >= 0 && col < WW)
            v = s[(long)c * HW + row * WW + col];
        tile[c][r][ci] = v;
    }
    __syncthreads();
    int x = tid & 127, yy = tid >> 7;
    float acc = bias[g];
    const float* wg = w + g * 2 * KS * KS;
    #pragma unroll
    for (int c = 0; c < 2; ++c)
        #pragma unroll
        for (int dy = 0; dy < KS; ++dy)
            #pragma unroll
            for (int dx = 0; dx < KS; ++dx)
                acc += wg[(c * KS + dy) * KS + dx] * tile[c][yy + dy][x + dx];
    long p = (long)(y0 + yy) * WW + x;
    if (g < split) p0[(long)b * b0 + (long)g * HW + p] = acc;
    else           p1[(long)b * b1 + (long)(g - split) * HW + p] = acc;
}

// ---------------- Gram + norms: per (b,h): S[d][e]=sum_n q[d,n]k[e,n]
__global__ __launch_bounds__(256) void gram_k(
    const float* __restrict__ q,   // [NB][128][HW]
    const float* __restrict__ k,   // [NB][128][HW]
    float* __restrict__ gbuf)      // [NB*8][288]: S(256), qq(16), kk(16)
{
    int bh = blockIdx.x;
    int chunk = blockIdx.y;          // 32 chunks of 512 pixels
    int b = bh >> 3, h = bh & 7;
    const float* qb = q + ((long)b * 128 + h * 16) * HW;
    const float* kb = k + ((long)b * 128 + h * 16) * HW;
    int pstart = chunk * 512;
    __shared__ float qs[16][64], ks[16][64];
    int tid = threadIdx.x;
    int d = tid >> 4, e = tid & 15;
    float s = 0.f, sq = 0.f, sk = 0.f;
    for (int p0 = pstart; p0 < pstart + 512; p0 += 64) {
        int r = tid >> 6;     // 0..3
        int cc = tid & 63;
        #pragma unroll
        for (int j = 0; j < 4; ++j) {
            qs[r + j * 4][cc] = qb[(long)(r + j * 4) * HW + p0 + cc];
            ks[r + j * 4][cc] = kb[(long)(r + j * 4) * HW + p0 + cc];
        }
        __syncthreads();
        #pragma unroll
        for (int p = 0; p < 64; ++p) {
            float qv = qs[d][p], kv = ks[e][p];
            s += qv * kv;
            if (d == e) { sq += qv * qv; sk += kv * kv; }
        }
        __syncthreads();
    }
    float* gb = gbuf + bh * 288;
    atomicAdd(&gb[d * 16 + e], s);
    if (d == e) { atomicAdd(&gb[256 + d], sq); atomicAdd(&gb[272 + d], sk); }
}

// ---------------- softmax + fold attention into proj weights
__global__ __launch_bounds__(256) void attn_fold(
    const float* __restrict__ gbuf, const float* __restrict__ temp,
    const float* __restrict__ projw,  // [128][256]
    float* __restrict__ wall)         // [NB][128][256]
{
    int bh = blockIdx.x;
    int b = bh >> 3, h = bh & 7;
    const float* gb = gbuf + bh * 288;
    __shared__ float logit[16][16];
    __shared__ float A[16][16];
    int tid = threadIdx.x;
    int d = tid >> 4, e = tid & 15;
    {
        float nq = fmaxf(sqrtf(gb[256 + d]), 1e-12f);
        float nk = fmaxf(sqrtf(gb[272 + e]), 1e-12f);
        logit[d][e] = gb[d * 16 + e] / (nq * nk) * temp[h];
    }
    __syncthreads();
    float m = -1e30f;
    #pragma unroll
    for (int j = 0; j < 16; ++j) m = fmaxf(m, logit[d][j]);
    float ex = expf(logit[d][e] - m);
    A[d][e] = ex;
    __syncthreads();
    float sum = 0.f;
    #pragma unroll
    for (int j = 0; j < 16; ++j) sum += A[d][j];
    __syncthreads();
    A[d][e] = ex / sum;
    __syncthreads();
    // wall[b][co][h*16+e] = sum_d projw[co][h*16+d] * A[d][e]
    int e2 = tid & 15, co0 = tid >> 4;
    for (int co = co0; co < 128; co += 16) {
        float sacc = 0.f;
        #pragma unroll
        for (int dd = 0; dd < 16; ++dd)
            sacc += projw[co * 256 + h * 16 + dd] * A[dd][e2];
        wall[((long)b * 128 + co) * 256 + h * 16 + e2] = sacc;
    }
    // copy static right half of proj (v-independent part untouched by attn)
    if (h == 0) {
        for (int idx = tid; idx < 128 * 128; idx += 256) {
            int co = idx >> 7, c = idx & 127;
            wall[((long)b * 128 + co) * 256 + 128 + c] = projw[co * 256 + 128 + c];
        }
    }
}

extern "C" void kernel_launch(void* const* d_in, const int* in_sizes, int n_in,
                              void* d_out, int out_size, void* d_ws, size_t ws_size,
                              hipStream_t stream) {
    const float* x      = (const float*)d_in[0];
    const float* pos_w  = (const float*)d_in[1];
    const float* pos_b  = (const float*)d_in[2];
    const float* qd3_w  = (const float*)d_in[3];
    const float* qd3_b  = (const float*)d_in[4];
    const float* qd5_w  = (const float*)d_in[5];
    const float* qd5_b  = (const float*)d_in[6];
    const float* temp   = (const float*)d_in[7];
    const float* d3_w   = (const float*)d_in[8];
    const float* d3_b   = (const float*)d_in[9];
    const float* d5_w   = (const float*)d_in[10];
    const float* d5_b   = (const float*)d_in[11];
    const float* proj_w = (const float*)d_in[12];
    float* out = (float*)d_out;
    float* ws  = (float*)d_ws;

    const long hw = HW;

    // Adaptive batch-chunking so scratch fits ws_size.
    // Per-batch floats: t 384*HW + vy 256*HW + kbuf 128*HW = 12,582,912
    // Plus per-batch wall 128*256, plus fixed gram 64*288.
    int NB = 8;
    while (NB > 1) {
        size_t need = (size_t)NB * (12582912UL + 32768UL) * 4UL + 73728UL * 4UL;
        if (need <= ws_size) break;
        NB >>= 1;
    }

    const long tN    = (long)NB * 384 * hw;
    const long vyN   = (long)NB * 256 * hw;
    const long kbufN = (long)NB * 128 * hw;
    float* t    = ws;
    float* vy   = t + tN;
    float* kbuf = vy + vyN;
    float* gram = kbuf + kbufN;
    float* wall = gram + 64 * 288;

    for (int b0 = 0; b0 < 8; b0 += NB) {
        const float* xb = x + (long)b0 * 128 * hw;
        float* outb = out + (long)b0 * 128 * hw;

        // K1: t = 1x1 conv(x) 128->384
        sgemm_bias<<<dim3(256, 6, NB), 256, 0, stream>>>(
            pos_w, xb, t, pos_b, 384, 128, HW, HW, 0L, 128 * hw, 384 * hw);

        // K2a: conv3(t): g<128 -> q (in outb), g in 128..191 -> k[0..63]
        gconv<3><<<dim3(64, 192, NB), 256, 0, stream>>>(
            t, 384, qd3_w, qd3_b, 128, outb, 128 * hw, kbuf, 128 * hw);

        // K2b: conv5(t): g<64 -> k[64+g], g>=64 -> v rows 0..127 of vy
        gconv<5><<<dim3(64, 192, NB), 256, 0, stream>>>(
            t, 384, qd5_w, qd5_b, 64, kbuf + 64 * hw, 128 * hw, vy, 256 * hw);

        // K3: Gram + norms
        zerok<<<(64 * 288 + 255) / 256, 256, 0, stream>>>(gram, 64 * 288);
        gram_k<<<dim3(NB * 8, 32), 256, 0, stream>>>(outb, kbuf, gram);

        // K4: softmax + fold into proj weights
        attn_fold<<<NB * 8, 256, 0, stream>>>(gram, temp, proj_w, wall);

        // K5a: d3(x) -> vy rows 128..191 ; d5(x) -> vy rows 192..255
        gconv<3><<<dim3(64, 64, NB), 256, 0, stream>>>(
            xb, 128, d3_w, d3_b, 64, vy + 128 * hw, 256 * hw, nullptr, 0);
        gconv<5><<<dim3(64, 64, NB), 256, 0, stream>>>(
            xb, 128, d5_w, d5_b, 64, vy + 192 * hw, 256 * hw, nullptr, 0);

        // K5b: final = Wall[b] @ [v; d3x; d5x]  (overwrites q scratch in outb)
        sgemm_bias<<<dim3(256, 2, NB), 256, 0, stream>>>(
            wall, vy, outb, nullptr, 128, 256, HW, HW, 128 * 256L, 256 * hw, 128 * hw);
    }
}

// Round 3
// 811.990 us; speedup vs baseline: 1.2435x; 1.2435x over previous
//
#include <hip/hip_runtime.h>
#include <hip/hip_bf16.h>

// ---------------------------------------------------------------------------
// Problem geometry (fixed): B=8, C=128, H=W=128, hw=16384, num_head=8
// Pipeline (per batch-chunk of NB batches, NB adaptive to ws_size):
//  K1: t = pos_w (1x1 conv, 128->384) + pos_b            [SGEMM 384xNB*hw x128]
//  K2a: conv3(t) grouped (192 groups of 2) -> q(128ch, in d_out), k(0..63)
//  K2b: conv5(t) grouped -> k(64..127), v(128ch)
//  K3: Gram S[16x16], |q|^2, |k|^2 per (b,h)  (MFMA bf16, atomic partials)
//  K4: A = softmax(S/(nq nk) * temp); fold into proj: Wall[b] = [proj_L@A | proj_R]
//  K5a: d3(x), d5(x) grouped convs -> vy rows 128..255
//  K5b: out = Wall[b] @ [v; d3x; d5x]                    [SGEMM 128xhw x256]
// ---------------------------------------------------------------------------

#define HW 16384
#define HH 128
#define WW 128

typedef __attribute__((ext_vector_type(8))) short bf16x8;
typedef __attribute__((ext_vector_type(4))) float f32x4;

__device__ inline short f2bf(float f) {
    unsigned u = __float_as_uint(f);
    return (short)((u + 0x7FFFu + ((u >> 16) & 1u)) >> 16);
}

__global__ void zerok(float* p, int n) {
    int i = blockIdx.x * 256 + threadIdx.x;
    if (i < n) p[i] = 0.f;
}

// ---------------- tiled f32 GEMM: C[m][n] = sum_k A[m][k]*B[k][n] (+bias[m])
__global__ __launch_bounds__(256) void sgemm_bias(
    const float* __restrict__ A, const float* __restrict__ B,
    float* __restrict__ C, const float* __restrict__ bias,
    int M, int K, int ldb, int ldc,
    long astride, long bstride, long cstride)
{
    int b = blockIdx.z;
    A += (long)b * astride;
    B += (long)b * bstride;
    C += (long)b * cstride;
    int m0 = blockIdx.y * 64, n0 = blockIdx.x * 64;
    __shared__ float As[16][64];
    __shared__ float Bs[16][64];
    int tid = threadIdx.x;
    int tx = tid & 15, ty = tid >> 4;
    float acc[4][4] = {};
    for (int k0 = 0; k0 < K; k0 += 16) {
        {   // A tile: As[kk][mm] = A[(m0+mm)*K + k0+kk]
            int mm = tid & 63;
            int kg = tid >> 6;       // 0..3
            #pragma unroll
            for (int j = 0; j < 4; ++j) {
                int kk = kg * 4 + j;
                As[kk][mm] = A[(long)(m0 + mm) * K + k0 + kk];
            }
        }
        {   // B tile: Bs[kk][nn] = B[(k0+kk)*ldb + n0+nn]
            int nn = tid & 63;
            int kg = tid >> 6;
            #pragma unroll
            for (int j = 0; j < 4; ++j) {
                int kk = kg + j * 4;
                Bs[kk][nn] = B[(long)(k0 + kk) * ldb + n0 + nn];
            }
        }
        __syncthreads();
        #pragma unroll
        for (int kk = 0; kk < 16; ++kk) {
            float a[4], bb[4];
            #pragma unroll
            for (int i = 0; i < 4; ++i) a[i] = As[kk][ty * 4 + i];
            #pragma unroll
            for (int j = 0; j < 4; ++j) bb[j] = Bs[kk][tx * 4 + j];
            #pragma unroll
            for (int i = 0; i < 4; ++i)
                #pragma unroll
                for (int j = 0; j < 4; ++j)
                    acc[i][j] += a[i] * bb[j];
        }
        __syncthreads();
    }
    #pragma unroll
    for (int i = 0; i < 4; ++i) {
        int m = m0 + ty * 4 + i;
        float bv = bias ? bias[m] : 0.f;
        #pragma unroll
        for (int j = 0; j < 4; ++j)
            C[(long)m * ldc + n0 + tx * 4 + j] = acc[i][j] + bv;
    }
}

// ---------------- grouped conv, 2 input channels per group, KSxKS, pad KS/2.
template<int KS>
__global__ __launch_bounds__(256) void gconv(
    const float* __restrict__ src, int srcC,
    const float* __restrict__ w,    // [G][2][KS][KS]
    const float* __restrict__ bias, // [G]
    int split,
    float* __restrict__ p0, long b0,
    float* __restrict__ p1, long b1)
{
    constexpr int PAD = KS / 2;
    constexpr int RW = 2 + 2 * PAD;      // staged rows for 2 output rows
    constexpr int W2 = WW + 2 * PAD;
    int g = blockIdx.y, b = blockIdx.z, y0 = blockIdx.x * 2;
    __shared__ float tile[2][RW][W2];
    const float* s = src + ((long)b * srcC + 2 * g) * HW;
    int tid = threadIdx.x;
    const int total = 2 * RW * W2;
    for (int idx = tid; idx < total; idx += 256) {
        int c = idx / (RW * W2);
        int rem = idx % (RW * W2);
        int r = rem / W2, ci = rem % W2;
        int col = ci - PAD;
        int row = y0 - PAD + r;
        float v = 0.f;
        if (row >= 0 && row < HH && col >= 0 && col < WW)
            v = s[(long)c * HW + row * WW + col];
        tile[c][r][ci] = v;
    }
    __syncthreads();
    int x = tid & 127, yy = tid >> 7;
    float acc = bias[g];
    const float* wg = w + g * 2 * KS * KS;
    #pragma unroll
    for (int c = 0; c < 2; ++c)
        #pragma unroll
        for (int dy = 0; dy < KS; ++dy)
            #pragma unroll
            for (int dx = 0; dx < KS; ++dx)
                acc += wg[(c * KS + dy) * KS + dx] * tile[c][yy + dy][x + dx];
    long p = (long)(y0 + yy) * WW + x;
    if (g < split) p0[(long)b * b0 + (long)g * HW + p] = acc;
    else           p1[(long)b * b1 + (long)(g - split) * HW + p] = acc;
}

// ---------------- Gram + norms via MFMA bf16:
// per (b,h): S[d][e] = sum_n q[d,n]*k[e,n]; qq[d]=|q[d]|^2; kk[e]=|k[e]|^2
// One wave per block. Lane l: row r=l&15, k-offset (l>>4)*8.
// Any consistent k-permutation in the A/B fragment mapping cancels (dot over k).
__global__ __launch_bounds__(64) void gram_mfma(
    const float* __restrict__ q,   // [NB][128][HW]
    const float* __restrict__ k,   // [NB][128][HW]
    float* __restrict__ gbuf)      // [NB*8][288]: S(256), qq(16), kk(16)
{
    int bh = blockIdx.x, chunk = blockIdx.y;
    int b = bh >> 3, h = bh & 7;
    int l = threadIdx.x;
    int r = l & 15, koff = (l >> 4) * 8;
    const float* qrow = q + ((long)b * 128 + h * 16 + r) * HW;
    const float* krow = k + ((long)b * 128 + h * 16 + r) * HW;
    f32x4 acc = {0.f, 0.f, 0.f, 0.f};
    float sq = 0.f, sk = 0.f;
    int n0 = chunk * 512;
    for (int n = n0; n < n0 + 512; n += 32) {
        float4 qa = *(const float4*)(qrow + n + koff);
        float4 qb = *(const float4*)(qrow + n + koff + 4);
        float4 ka = *(const float4*)(krow + n + koff);
        float4 kb = *(const float4*)(krow + n + koff + 4);
        bf16x8 af, bf;
        af[0] = f2bf(qa.x); af[1] = f2bf(qa.y); af[2] = f2bf(qa.z); af[3] = f2bf(qa.w);
        af[4] = f2bf(qb.x); af[5] = f2bf(qb.y); af[6] = f2bf(qb.z); af[7] = f2bf(qb.w);
        bf[0] = f2bf(ka.x); bf[1] = f2bf(ka.y); bf[2] = f2bf(ka.z); bf[3] = f2bf(ka.w);
        bf[4] = f2bf(kb.x); bf[5] = f2bf(kb.y); bf[6] = f2bf(kb.z); bf[7] = f2bf(kb.w);
        sq += qa.x*qa.x + qa.y*qa.y + qa.z*qa.z + qa.w*qa.w
            + qb.x*qb.x + qb.y*qb.y + qb.z*qb.z + qb.w*qb.w;
        sk += ka.x*ka.x + ka.y*ka.y + ka.z*ka.z + ka.w*ka.w
            + kb.x*kb.x + kb.y*kb.y + kb.z*kb.z + kb.w*kb.w;
        acc = __builtin_amdgcn_mfma_f32_16x16x32_bf16(af, bf, acc, 0, 0, 0);
    }
    float* gb = gbuf + bh * 288;
    #pragma unroll
    for (int reg = 0; reg < 4; ++reg) {
        int row = (l >> 4) * 4 + reg;        // C/D: col=lane&15, row=(lane>>4)*4+reg
        atomicAdd(&gb[row * 16 + r], acc[reg]);
    }
    sq += __shfl_xor(sq, 16); sq += __shfl_xor(sq, 32);
    sk += __shfl_xor(sk, 16); sk += __shfl_xor(sk, 32);
    if (l < 16) { atomicAdd(&gb[256 + r], sq); atomicAdd(&gb[272 + r], sk); }
}

// ---------------- softmax + fold attention into proj weights
__global__ __launch_bounds__(256) void attn_fold(
    const float* __restrict__ gbuf, const float* __restrict__ temp,
    const float* __restrict__ projw,  // [128][256]
    float* __restrict__ wall)         // [NB][128][256]
{
    int bh = blockIdx.x;
    int b = bh >> 3, h = bh & 7;
    const float* gb = gbuf + bh * 288;
    __shared__ float logit[16][16];
    __shared__ float A[16][16];
    int tid = threadIdx.x;
    int d = tid >> 4, e = tid & 15;
    {
        float nq = fmaxf(sqrtf(gb[256 + d]), 1e-12f);
        float nk = fmaxf(sqrtf(gb[272 + e]), 1e-12f);
        logit[d][e] = gb[d * 16 + e] / (nq * nk) * temp[h];
    }
    __syncthreads();
    float m = -1e30f;
    #pragma unroll
    for (int j = 0; j < 16; ++j) m = fmaxf(m, logit[d][j]);
    float ex = expf(logit[d][e] - m);
    A[d][e] = ex;
    __syncthreads();
    float sum = 0.f;
    #pragma unroll
    for (int j = 0; j < 16; ++j) sum += A[d][j];
    __syncthreads();
    A[d][e] = ex / sum;
    __syncthreads();
    // wall[b][co][h*16+e] = sum_d projw[co][h*16+d] * A[d][e]
    int e2 = tid & 15, co0 = tid >> 4;
    for (int co = co0; co < 128; co += 16) {
        float sacc = 0.f;
        #pragma unroll
        for (int dd = 0; dd < 16; ++dd)
            sacc += projw[co * 256 + h * 16 + dd] * A[dd][e2];
        wall[((long)b * 128 + co) * 256 + h * 16 + e2] = sacc;
    }
    // copy static right half of proj (v-independent part untouched by attn)
    if (h == 0) {
        for (int idx = tid; idx < 128 * 128; idx += 256) {
            int co = idx >> 7, c = idx & 127;
            wall[((long)b * 128 + co) * 256 + 128 + c] = projw[co * 256 + 128 + c];
        }
    }
}

extern "C" void kernel_launch(void* const* d_in, const int* in_sizes, int n_in,
                              void* d_out, int out_size, void* d_ws, size_t ws_size,
                              hipStream_t stream) {
    const float* x      = (const float*)d_in[0];
    const float* pos_w  = (const float*)d_in[1];
    const float* pos_b  = (const float*)d_in[2];
    const float* qd3_w  = (const float*)d_in[3];
    const float* qd3_b  = (const float*)d_in[4];
    const float* qd5_w  = (const float*)d_in[5];
    const float* qd5_b  = (const float*)d_in[6];
    const float* temp   = (const float*)d_in[7];
    const float* d3_w   = (const float*)d_in[8];
    const float* d3_b   = (const float*)d_in[9];
    const float* d5_w   = (const float*)d_in[10];
    const float* d5_b   = (const float*)d_in[11];
    const float* proj_w = (const float*)d_in[12];
    float* out = (float*)d_out;
    float* ws  = (float*)d_ws;

    const long hw = HW;

    // Adaptive batch-chunking so scratch fits ws_size.
    int NB = 8;
    while (NB > 1) {
        size_t need = (size_t)NB * (12582912UL + 32768UL) * 4UL + 73728UL * 4UL;
        if (need <= ws_size) break;
        NB >>= 1;
    }

    const long tN    = (long)NB * 384 * hw;
    const long vyN   = (long)NB * 256 * hw;
    const long kbufN = (long)NB * 128 * hw;
    float* t    = ws;
    float* vy   = t + tN;
    float* kbuf = vy + vyN;
    float* gram = kbuf + kbufN;
    float* wall = gram + 64 * 288;

    for (int b0 = 0; b0 < 8; b0 += NB) {
        const float* xb = x + (long)b0 * 128 * hw;
        float* outb = out + (long)b0 * 128 * hw;

        // K1: t = 1x1 conv(x) 128->384
        sgemm_bias<<<dim3(256, 6, NB), 256, 0, stream>>>(
            pos_w, xb, t, pos_b, 384, 128, HW, HW, 0L, 128 * hw, 384 * hw);

        // K2a: conv3(t): g<128 -> q (in outb), g in 128..191 -> k[0..63]
        gconv<3><<<dim3(64, 192, NB), 256, 0, stream>>>(
            t, 384, qd3_w, qd3_b, 128, outb, 128 * hw, kbuf, 128 * hw);

        // K2b: conv5(t): g<64 -> k[64+g], g>=64 -> v rows 0..127 of vy
        gconv<5><<<dim3(64, 192, NB), 256, 0, stream>>>(
            t, 384, qd5_w, qd5_b, 64, kbuf + 64 * hw, 128 * hw, vy, 256 * hw);

        // K3: Gram + norms (MFMA)
        zerok<<<(64 * 288 + 255) / 256, 256, 0, stream>>>(gram, 64 * 288);
        gram_mfma<<<dim3(NB * 8, 32), 64, 0, stream>>>(outb, kbuf, gram);

        // K4: softmax + fold into proj weights
        attn_fold<<<NB * 8, 256, 0, stream>>>(gram, temp, proj_w, wall);

        // K5a: d3(x) -> vy rows 128..191 ; d5(x) -> vy rows 192..255
        gconv<3><<<dim3(64, 64, NB), 256, 0, stream>>>(
            xb, 128, d3_w, d3_b, 64, vy + 128 * hw, 256 * hw, nullptr, 0);
        gconv<5><<<dim3(64, 64, NB), 256, 0, stream>>>(
            xb, 128, d5_w, d5_b, 64, vy + 192 * hw, 256 * hw, nullptr, 0);

        // K5b: final = Wall[b] @ [v; d3x; d5x]  (overwrites q scratch in outb)
        sgemm_bias<<<dim3(256, 2, NB), 256, 0, stream>>>(
            wall, vy, outb, nullptr, 128, 256, HW, HW, 128 * 256L, 256 * hw, 128 * hw);
    }
}

// Round 4
// 383.693 us; speedup vs baseline: 2.6315x; 2.1163x over previous
//
#include <hip/hip_runtime.h>
#include <hip/hip_bf16.h>

// ---------------------------------------------------------------------------
// B=8, C=128, H=W=128, hw=16384, heads=8. All intermediates bf16.
//  packw (once): poswpk[384][64] u32 = bf16-pair-packed pos_w
//  K1 gemm_t:  t[384][HW] bf16 = pos_w @ x + pos_b        (MFMA)
//  K2 dualconv<t>: conv3+conv5 on t (group-pairs) -> q,k,v bf16
//  K3 gram: S[16][16], |q|^2,|k|^2 per (b,h)              (MFMA)
//  K4 attn_fold: softmax fold -> wallpk[128][128] u32 (bf16 pairs)
//  K5a dualconv<x>: conv3+conv5 on x -> vy rows 128..255
//  K5b gemm_out: out f32 = wallpk @ vy                    (MFMA)
// ---------------------------------------------------------------------------

#define HW 16384
#define HH 128
#define WW 128

typedef __attribute__((ext_vector_type(8))) short bf16x8;
typedef __attribute__((ext_vector_type(4))) float f32x4;
typedef __attribute__((ext_vector_type(4))) unsigned short us4;

__device__ inline unsigned short f2bf(float f) {
    unsigned u = __float_as_uint(f);
    return (unsigned short)((u + 0x7FFFu + ((u >> 16) & 1u)) >> 16);
}
__device__ inline float bf2f(unsigned short us) {
    return __uint_as_float(((unsigned)us) << 16);
}
__device__ inline unsigned packbf(float lo, float hi) {
    return (unsigned)f2bf(lo) | ((unsigned)f2bf(hi) << 16);
}

__global__ void zerok(float* p, int n) {
    int i = blockIdx.x * 256 + threadIdx.x;
    if (i < n) p[i] = 0.f;
}

// pack pos_w [384][128] f32 -> poswpk [384][64] u32
__global__ __launch_bounds__(256) void packw(const float* __restrict__ w,
                                             unsigned* __restrict__ wpk) {
    int id = blockIdx.x * 256 + threadIdx.x;   // 384*64
    if (id >= 384 * 64) return;
    int m = id >> 6, kp = id & 63;
    wpk[id] = packbf(w[m * 128 + 2 * kp], w[m * 128 + 2 * kp + 1]);
}

// ---------------- K1: t = pos_w @ x + b  (M=384, K=128, N=HW), bf16 out
__global__ __launch_bounds__(256) void gemm_t(
    const unsigned* __restrict__ wpk,   // [384][64] u32 (L2)
    const float* __restrict__ x,        // [NB][128][HW]
    const float* __restrict__ posb,     // [384]
    unsigned short* __restrict__ t)     // [NB][384][HW]
{
    int b = blockIdx.z;
    int n0 = blockIdx.x * 32;
    const float* xb = x + (long)b * 128 * HW;
    unsigned short* tb = t + (long)b * 384 * HW;
    __shared__ unsigned Bs[32][69];     // [n][kpair], pad->row stride 69
    int tid = threadIdx.x;
    int oct = tid & 7, kpb = tid >> 3;
    #pragma unroll
    for (int p = 0; p < 2; ++p) {
        int kp = p * 32 + kpb;
        float4 lo = *(const float4*)(xb + (long)(2 * kp) * HW + n0 + oct * 4);
        float4 hi = *(const float4*)(xb + (long)(2 * kp + 1) * HW + n0 + oct * 4);
        Bs[oct * 4 + 0][kp] = packbf(lo.x, hi.x);
        Bs[oct * 4 + 1][kp] = packbf(lo.y, hi.y);
        Bs[oct * 4 + 2][kp] = packbf(lo.z, hi.z);
        Bs[oct * 4 + 3][kp] = packbf(lo.w, hi.w);
    }
    __syncthreads();
    int w = tid >> 6, l = tid & 63;
    int lr = l & 15, lg = l >> 4;
    f32x4 acc[6][2] = {};
    #pragma unroll
    for (int kk = 0; kk < 4; ++kk) {
        bf16x8 af[6];
        #pragma unroll
        for (int mt = 0; mt < 6; ++mt) {
            int m = (w * 6 + mt) * 16 + lr;
            af[mt] = *(const bf16x8*)(wpk + (long)m * 64 + kk * 16 + lg * 4);
        }
        #pragma unroll
        for (int ns = 0; ns < 2; ++ns) {
            bf16x8 bf = *(const bf16x8*)(&Bs[ns * 16 + lr][kk * 16 + lg * 4]);
            #pragma unroll
            for (int mt = 0; mt < 6; ++mt)
                acc[mt][ns] = __builtin_amdgcn_mfma_f32_16x16x32_bf16(
                    af[mt], bf, acc[mt][ns], 0, 0, 0);
        }
    }
    #pragma unroll
    for (int mt = 0; mt < 6; ++mt)
        #pragma unroll
        for (int ns = 0; ns < 2; ++ns)
            #pragma unroll
            for (int reg = 0; reg < 4; ++reg) {
                int m = (w * 6 + mt) * 16 + lg * 4 + reg;
                float v = acc[mt][ns][reg] + posb[m];
                tb[(long)m * HW + n0 + ns * 16 + lr] = f2bf(v);
            }
}

// ---------------- merged conv3+conv5, 2 groups (one group-pair) per block
template<bool SRCBF>
__global__ __launch_bounds__(256) void dualconv(
    const void* __restrict__ src_, int srcC,
    const float* __restrict__ w3, const float* __restrict__ b3, // [G3][2][3][3]
    const float* __restrict__ w5, const float* __restrict__ b5, // [G5][2][5][5]
    int s3, unsigned short* __restrict__ r3a, long st3a,
    unsigned short* __restrict__ r3b, long st3b,
    int s5, unsigned short* __restrict__ r5a, long st5a,
    unsigned short* __restrict__ r5b, long st5b)
{
    int gp = blockIdx.y, b = blockIdx.z, y0 = blockIdx.x * 8;
    __shared__ __align__(16) float tile[4][12][132];   // ch, rows y0-2..y0+9, col -2..129
    int tid = threadIdx.x;
    int c0 = 4 * gp;
    const unsigned short* sB = (const unsigned short*)src_ + (long)b * srcC * HW;
    const float* sF = (const float*)src_ + (long)b * srcC * HW;
    const int TOT = 4 * 12 * 132;
    for (int idx = tid; idx < TOT; idx += 256) {
        int c = idx / (12 * 132);
        int rem = idx - c * (12 * 132);
        int r = rem / 132, ci = rem - r * 132;
        int row = y0 + r - 2, col = ci - 2;
        float v = 0.f;
        if (row >= 0 && row < HH && col >= 0 && col < WW) {
            long off = (long)(c0 + c) * HW + row * WW + col;
            v = SRCBF ? bf2f(sB[off]) : sF[off];
        }
        tile[c][r][ci] = v;
    }
    __syncthreads();
    int xq = tid & 31, yy = tid >> 5;
    int x0 = xq * 4;
    float a3[2][4], a5[2][4];
    #pragma unroll
    for (int gi = 0; gi < 2; ++gi) {
        int g = 2 * gp + gi;
        #pragma unroll
        for (int j = 0; j < 4; ++j) { a3[gi][j] = b3[g]; a5[gi][j] = b5[g]; }
        #pragma unroll
        for (int c = 0; c < 2; ++c) {
            const float* W5 = w5 + (g * 2 + c) * 25;
            const float* W3 = w3 + (g * 2 + c) * 9;
            float w5v[5][5], w3v[3][3];
            #pragma unroll
            for (int dy = 0; dy < 5; ++dy)
                #pragma unroll
                for (int dx = 0; dx < 5; ++dx) w5v[dy][dx] = W5[dy * 5 + dx];
            #pragma unroll
            for (int dy = 0; dy < 3; ++dy)
                #pragma unroll
                for (int dx = 0; dx < 3; ++dx) w3v[dy][dx] = W3[dy * 3 + dx];
            #pragma unroll
            for (int r = 0; r < 5; ++r) {
                const float* p = &tile[2 * gi + c][yy + r][x0];
                float win[8];
                *(float4*)win = *(const float4*)p;
                *(float4*)(win + 4) = *(const float4*)(p + 4);
                #pragma unroll
                for (int dx = 0; dx < 5; ++dx)
                    #pragma unroll
                    for (int j = 0; j < 4; ++j)
                        a5[gi][j] += w5v[r][dx] * win[j + dx];
                if (r >= 1 && r <= 3) {
                    #pragma unroll
                    for (int dx = 0; dx < 3; ++dx)
                        #pragma unroll
                        for (int j = 0; j < 4; ++j)
                            a3[gi][j] += w3v[r - 1][dx] * win[j + dx + 1];
                }
            }
        }
    }
    long prow = (long)(y0 + yy) * WW + x0;
    #pragma unroll
    for (int gi = 0; gi < 2; ++gi) {
        int g = 2 * gp + gi;
        us4 v3, v5;
        #pragma unroll
        for (int j = 0; j < 4; ++j) { v3[j] = f2bf(a3[gi][j]); v5[j] = f2bf(a5[gi][j]); }
        unsigned short* d3 = (g < s3) ? r3a + (long)b * st3a + (long)g * HW
                                      : r3b + (long)b * st3b + (long)(g - s3) * HW;
        unsigned short* d5 = (g < s5) ? r5a + (long)b * st5a + (long)g * HW
                                      : r5b + (long)b * st5b + (long)(g - s5) * HW;
        *(us4*)(d3 + prow) = v3;
        *(us4*)(d5 + prow) = v5;
    }
}

// ---------------- Gram + norms (bf16 in, MFMA)
__global__ __launch_bounds__(64) void gram_mfma(
    const unsigned short* __restrict__ q,  // [NB][128][HW]
    const unsigned short* __restrict__ k,
    float* __restrict__ gbuf)              // [NB*8][288]
{
    int bh = blockIdx.x, chunk = blockIdx.y;
    int b = bh >> 3, h = bh & 7;
    int l = threadIdx.x;
    int r = l & 15, koff = (l >> 4) * 8;
    const unsigned short* qrow = q + ((long)b * 128 + h * 16 + r) * HW;
    const unsigned short* krow = k + ((long)b * 128 + h * 16 + r) * HW;
    f32x4 acc = {0.f, 0.f, 0.f, 0.f};
    float sq = 0.f, sk = 0.f;
    int n0 = chunk * 512;
    for (int n = n0; n < n0 + 512; n += 32) {
        bf16x8 af = *(const bf16x8*)(qrow + n + koff);
        bf16x8 bf = *(const bf16x8*)(krow + n + koff);
        #pragma unroll
        for (int j = 0; j < 8; ++j) {
            float fq = bf2f((unsigned short)af[j]);
            float fk = bf2f((unsigned short)bf[j]);
            sq += fq * fq; sk += fk * fk;
        }
        acc = __builtin_amdgcn_mfma_f32_16x16x32_bf16(af, bf, acc, 0, 0, 0);
    }
    float* gb = gbuf + bh * 288;
    #pragma unroll
    for (int reg = 0; reg < 4; ++reg) {
        int row = (l >> 4) * 4 + reg;
        atomicAdd(&gb[row * 16 + r], acc[reg]);
    }
    sq += __shfl_xor(sq, 16); sq += __shfl_xor(sq, 32);
    sk += __shfl_xor(sk, 16); sk += __shfl_xor(sk, 32);
    if (l < 16) { atomicAdd(&gb[256 + r], sq); atomicAdd(&gb[272 + r], sk); }
}

// ---------------- softmax + fold into packed bf16 proj weights
__global__ __launch_bounds__(256) void attn_fold(
    const float* __restrict__ gbuf, const float* __restrict__ temp,
    const float* __restrict__ projw,     // [128][256]
    unsigned* __restrict__ wallpk)       // [NB][128][128] u32 bf16-pairs
{
    int bh = blockIdx.x;
    int b = bh >> 3, h = bh & 7;
    const float* gb = gbuf + bh * 288;
    __shared__ float logit[16][16];
    __shared__ float A[16][16];
    int tid = threadIdx.x;
    int d = tid >> 4, e = tid & 15;
    {
        float nq = fmaxf(sqrtf(gb[256 + d]), 1e-12f);
        float nk = fmaxf(sqrtf(gb[272 + e]), 1e-12f);
        logit[d][e] = gb[d * 16 + e] / (nq * nk) * temp[h];
    }
    __syncthreads();
    float m = -1e30f;
    #pragma unroll
    for (int j = 0; j < 16; ++j) m = fmaxf(m, logit[d][j]);
    float ex = expf(logit[d][e] - m);
    A[d][e] = ex;
    __syncthreads();
    float sum = 0.f;
    #pragma unroll
    for (int j = 0; j < 16; ++j) sum += A[d][j];
    __syncthreads();
    A[d][e] = ex / sum;
    __syncthreads();
    // left half: wallpk[co][h*8+ep] = pack over e-pairs of sum_d proj*A
    int ep = tid & 7, co0 = tid >> 3;       // co0 0..31
    for (int co = co0; co < 128; co += 32) {
        float lo = 0.f, hi = 0.f;
        #pragma unroll
        for (int dd = 0; dd < 16; ++dd) {
            float pw = projw[co * 256 + h * 16 + dd];
            lo += pw * A[dd][2 * ep];
            hi += pw * A[dd][2 * ep + 1];
        }
        wallpk[((long)b * 128 + co) * 128 + h * 8 + ep] = packbf(lo, hi);
    }
    // right half (static): once per batch
    if (h == 0) {
        for (int idx = tid; idx < 128 * 64; idx += 256) {
            int co = idx >> 6, cp = idx & 63;
            wallpk[((long)b * 128 + co) * 128 + 64 + cp] =
                packbf(projw[co * 256 + 128 + 2 * cp], projw[co * 256 + 129 + 2 * cp]);
        }
    }
}

// ---------------- K5b: out f32 = wallpk @ vy  (M=128, K=256, N=HW)
__global__ __launch_bounds__(256) void gemm_out(
    const unsigned* __restrict__ wpk,       // [NB][128][128] u32 (L2)
    const unsigned short* __restrict__ vy,  // [NB][256][HW] bf16
    float* __restrict__ out)                // [NB][128][HW]
{
    int b = blockIdx.z;
    int n0 = blockIdx.x * 32;
    const unsigned* wb = wpk + (long)b * 128 * 128;
    const unsigned short* vyb = vy + (long)b * 256 * HW;
    float* ob = out + (long)b * 128 * HW;
    __shared__ unsigned Bs[32][129];
    int tid = threadIdx.x;
    int oct = tid & 7, kpb = tid >> 3;
    #pragma unroll
    for (int p = 0; p < 4; ++p) {
        int kp = p * 32 + kpb;
        us4 lo = *(const us4*)(vyb + (long)(2 * kp) * HW + n0 + oct * 4);
        us4 hi = *(const us4*)(vyb + (long)(2 * kp + 1) * HW + n0 + oct * 4);
        #pragma unroll
        for (int j = 0; j < 4; ++j)
            Bs[oct * 4 + j][kp] = (unsigned)lo[j] | ((unsigned)hi[j] << 16);
    }
    __syncthreads();
    int w = tid >> 6, l = tid & 63;
    int lr = l & 15, lg = l >> 4;
    f32x4 acc[2][2] = {};
    #pragma unroll
    for (int kk = 0; kk < 8; ++kk) {
        bf16x8 af[2];
        #pragma unroll
        for (int i = 0; i < 2; ++i) {
            int m = (w * 2 + i) * 16 + lr;
            af[i] = *(const bf16x8*)(wb + (long)m * 128 + kk * 16 + lg * 4);
        }
        #pragma unroll
        for (int ns = 0; ns < 2; ++ns) {
            bf16x8 bf = *(const bf16x8*)(&Bs[ns * 16 + lr][kk * 16 + lg * 4]);
            #pragma unroll
            for (int i = 0; i < 2; ++i)
                acc[i][ns] = __builtin_amdgcn_mfma_f32_16x16x32_bf16(
                    af[i], bf, acc[i][ns], 0, 0, 0);
        }
    }
    #pragma unroll
    for (int i = 0; i < 2; ++i)
        #pragma unroll
        for (int ns = 0; ns < 2; ++ns)
            #pragma unroll
            for (int reg = 0; reg < 4; ++reg) {
                int m = (w * 2 + i) * 16 + lg * 4 + reg;
                ob[(long)m * HW + n0 + ns * 16 + lr] = acc[i][ns][reg];
            }
}

extern "C" void kernel_launch(void* const* d_in, const int* in_sizes, int n_in,
                              void* d_out, int out_size, void* d_ws, size_t ws_size,
                              hipStream_t stream) {
    const float* x      = (const float*)d_in[0];
    const float* pos_w  = (const float*)d_in[1];
    const float* pos_b  = (const float*)d_in[2];
    const float* qd3_w  = (const float*)d_in[3];
    const float* qd3_b  = (const float*)d_in[4];
    const float* qd5_w  = (const float*)d_in[5];
    const float* qd5_b  = (const float*)d_in[6];
    const float* temp   = (const float*)d_in[7];
    const float* d3_w   = (const float*)d_in[8];
    const float* d3_b   = (const float*)d_in[9];
    const float* d5_w   = (const float*)d_in[10];
    const float* d5_b   = (const float*)d_in[11];
    const float* proj_w = (const float*)d_in[12];
    float* out = (float*)d_out;

    // per-batch scratch: t 384ch + q 128 + k 128 + vy 256 (bf16) + wallpk
    size_t perb = 896UL * HW * 2 + 128UL * 128 * 4;
    size_t fixedb = 64UL * 288 * 4 + 384UL * 64 * 4;
    int NB = 8;
    while (NB > 1 && (size_t)NB * perb + fixedb > ws_size) NB >>= 1;

    char* base = (char*)d_ws;
    unsigned short* t  = (unsigned short*)base; base += (size_t)NB * 384 * HW * 2;
    unsigned short* qb = (unsigned short*)base; base += (size_t)NB * 128 * HW * 2;
    unsigned short* kb = (unsigned short*)base; base += (size_t)NB * 128 * HW * 2;
    unsigned short* vy = (unsigned short*)base; base += (size_t)NB * 256 * HW * 2;
    unsigned* wallpk   = (unsigned*)base;       base += (size_t)NB * 128 * 128 * 4;
    float* gram        = (float*)base;          base += 64UL * 288 * 4;
    unsigned* poswpk   = (unsigned*)base;

    packw<<<(384 * 64 + 255) / 256, 256, 0, stream>>>(pos_w, poswpk);

    for (int b0 = 0; b0 < 8; b0 += NB) {
        const float* xb = x + (long)b0 * 128 * HW;
        float* outb = out + (long)b0 * 128 * HW;

        gemm_t<<<dim3(HW / 32, 1, NB), 256, 0, stream>>>(poswpk, xb, pos_b, t);

        // conv3 on t: g<128 -> q ; g>=128 -> k rows 0..63
        // conv5 on t: g<64 -> k rows 64..127 ; g>=64 -> vy rows 0..127
        dualconv<true><<<dim3(16, 96, NB), 256, 0, stream>>>(
            t, 384, qd3_w, qd3_b, qd5_w, qd5_b,
            128, qb, 128L * HW, kb, 128L * HW,
            64, kb + 64L * HW, 128L * HW, vy, 256L * HW);

        zerok<<<(64 * 288 + 255) / 256, 256, 0, stream>>>(gram, 64 * 288);
        gram_mfma<<<dim3(NB * 8, 32), 64, 0, stream>>>(qb, kb, gram);
        attn_fold<<<NB * 8, 256, 0, stream>>>(gram, temp, proj_w, wallpk);

        // conv3 on x -> vy rows 128..191 ; conv5 on x -> vy rows 192..255
        dualconv<false><<<dim3(16, 32, NB), 256, 0, stream>>>(
            xb, 128, d3_w, d3_b, d5_w, d5_b,
            64, vy + 128L * HW, 256L * HW, vy + 128L * HW, 256L * HW,
            64, vy + 192L * HW, 256L * HW, vy + 192L * HW, 256L * HW);

        gemm_out<<<dim3(HW / 32, 1, NB), 256, 0, stream>>>(wallpk, vy, outb);
    }
}

// Round 5
// 280.553 us; speedup vs baseline: 3.5989x; 1.3676x over previous
//
#include <hip/hip_runtime.h>
#include <hip/hip_bf16.h>

// ---------------------------------------------------------------------------
// B=8, C=128, H=W=128, hw=16384, heads=8.
//  packw (once): poswpk[384][64] u32 = bf16-pair-packed pos_w
//  packcw (once): conv weights f16-channel-pair packed
//  K1 gemm_t:  t[384][HW] f16 = pos_w @ x + pos_b         (MFMA, f16 out)
//  K2 dualconv<t>: conv3+conv5 on t via v_dot2_f32_f16 -> q,k,v bf16
//  K3 gram: S[16][16], |q|^2,|k|^2 per (b,h)              (MFMA)
//  K4 attn_fold: softmax fold -> wallpk[128][128] u32 (bf16 pairs)
//  K5a dualconv<x>: conv3+conv5 on x -> vy rows 128..255
//  K5b gemm_out: out f32 = wallpk @ vy                    (MFMA)
// ---------------------------------------------------------------------------

#define HW 16384
#define HH 128
#define WW 128

typedef __attribute__((ext_vector_type(8))) short bf16x8;
typedef __attribute__((ext_vector_type(4))) float f32x4;
typedef __attribute__((ext_vector_type(4))) unsigned short us4;
typedef _Float16 half2t __attribute__((ext_vector_type(2)));

__device__ inline unsigned short f2bf(float f) {
    unsigned u = __float_as_uint(f);
    return (unsigned short)((u + 0x7FFFu + ((u >> 16) & 1u)) >> 16);
}
__device__ inline float bf2f(unsigned short us) {
    return __uint_as_float(((unsigned)us) << 16);
}
__device__ inline unsigned packbf(float lo, float hi) {
    return (unsigned)f2bf(lo) | ((unsigned)f2bf(hi) << 16);
}
__device__ inline unsigned short f2h(float f) {
    _Float16 h = (_Float16)f;
    return __builtin_bit_cast(unsigned short, h);
}
__device__ inline unsigned packh(float lo, float hi) {
    return (unsigned)f2h(lo) | ((unsigned)f2h(hi) << 16);
}

#if defined(__has_builtin)
#if __has_builtin(__builtin_amdgcn_fdot2)
#define HAVE_FDOT2 1
#endif
#endif

__device__ inline float dot2acc(unsigned a, unsigned b, float c) {
#ifdef HAVE_FDOT2
    return __builtin_amdgcn_fdot2(__builtin_bit_cast(half2t, a),
                                  __builtin_bit_cast(half2t, b), c, false);
#else
    half2t ha = __builtin_bit_cast(half2t, a);
    half2t hb = __builtin_bit_cast(half2t, b);
    return c + (float)ha[0] * (float)hb[0] + (float)ha[1] * (float)hb[1];
#endif
}

__global__ void zerok(float* p, int n) {
    int i = blockIdx.x * 256 + threadIdx.x;
    if (i < n) p[i] = 0.f;
}

// pack pos_w [384][128] f32 -> poswpk [384][64] u32 (bf16 pairs along k)
__global__ __launch_bounds__(256) void packw(const float* __restrict__ w,
                                             unsigned* __restrict__ wpk) {
    int id = blockIdx.x * 256 + threadIdx.x;   // 384*64
    if (id >= 384 * 64) return;
    int m = id >> 6, kp = id & 63;
    wpk[id] = packbf(w[m * 128 + 2 * kp], w[m * 128 + 2 * kp + 1]);
}

// pack conv weights: channel-pair (c=0 lo, c=1 hi) f16 per tap.
// layout in cwpk: qd3[192*9] | qd5[192*25] | d3[64*9] | d5[64*25]
__global__ __launch_bounds__(256) void packcw(
    const float* __restrict__ qd3, const float* __restrict__ qd5,
    const float* __restrict__ d3, const float* __restrict__ d5,
    unsigned* __restrict__ o) {
    int id = blockIdx.x * 256 + threadIdx.x;
    if (id < 192 * 9) {
        int g = id / 9, tp = id % 9;
        o[id] = packh(qd3[(g * 2) * 9 + tp], qd3[(g * 2 + 1) * 9 + tp]);
    } else if (id < 192 * 9 + 192 * 25) {
        int r = id - 192 * 9; int g = r / 25, tp = r % 25;
        o[id] = packh(qd5[(g * 2) * 25 + tp], qd5[(g * 2 + 1) * 25 + tp]);
    } else if (id < 192 * 9 + 192 * 25 + 64 * 9) {
        int r = id - 192 * 9 - 192 * 25; int g = r / 9, tp = r % 9;
        o[id] = packh(d3[(g * 2) * 9 + tp], d3[(g * 2 + 1) * 9 + tp]);
    } else if (id < 192 * 9 + 192 * 25 + 64 * 9 + 64 * 25) {
        int r = id - 192 * 9 - 192 * 25 - 64 * 9; int g = r / 25, tp = r % 25;
        o[id] = packh(d5[(g * 2) * 25 + tp], d5[(g * 2 + 1) * 25 + tp]);
    }
}

// ---------------- K1: t = pos_w @ x + b  (M=384, K=128, N=HW), f16 out
__global__ __launch_bounds__(256) void gemm_t(
    const unsigned* __restrict__ wpk,   // [384][64] u32 (L2)
    const float* __restrict__ x,        // [NB][128][HW]
    const float* __restrict__ posb,     // [384]
    unsigned short* __restrict__ t)     // [NB][384][HW] f16
{
    int b = blockIdx.z;
    int n0 = blockIdx.x * 32;
    const float* xb = x + (long)b * 128 * HW;
    unsigned short* tb = t + (long)b * 384 * HW;
    __shared__ unsigned Bs[32][69];
    int tid = threadIdx.x;
    int oct = tid & 7, kpb = tid >> 3;
    #pragma unroll
    for (int p = 0; p < 2; ++p) {
        int kp = p * 32 + kpb;
        float4 lo = *(const float4*)(xb + (long)(2 * kp) * HW + n0 + oct * 4);
        float4 hi = *(const float4*)(xb + (long)(2 * kp + 1) * HW + n0 + oct * 4);
        Bs[oct * 4 + 0][kp] = packbf(lo.x, hi.x);
        Bs[oct * 4 + 1][kp] = packbf(lo.y, hi.y);
        Bs[oct * 4 + 2][kp] = packbf(lo.z, hi.z);
        Bs[oct * 4 + 3][kp] = packbf(lo.w, hi.w);
    }
    __syncthreads();
    int w = tid >> 6, l = tid & 63;
    int lr = l & 15, lg = l >> 4;
    f32x4 acc[6][2] = {};
    #pragma unroll
    for (int kk = 0; kk < 4; ++kk) {
        bf16x8 af[6];
        #pragma unroll
        for (int mt = 0; mt < 6; ++mt) {
            int m = (w * 6 + mt) * 16 + lr;
            af[mt] = *(const bf16x8*)(wpk + (long)m * 64 + kk * 16 + lg * 4);
        }
        #pragma unroll
        for (int ns = 0; ns < 2; ++ns) {
            bf16x8 bf = *(const bf16x8*)(&Bs[ns * 16 + lr][kk * 16 + lg * 4]);
            #pragma unroll
            for (int mt = 0; mt < 6; ++mt)
                acc[mt][ns] = __builtin_amdgcn_mfma_f32_16x16x32_bf16(
                    af[mt], bf, acc[mt][ns], 0, 0, 0);
        }
    }
    #pragma unroll
    for (int mt = 0; mt < 6; ++mt)
        #pragma unroll
        for (int ns = 0; ns < 2; ++ns)
            #pragma unroll
            for (int reg = 0; reg < 4; ++reg) {
                int m = (w * 6 + mt) * 16 + lg * 4 + reg;
                float v = acc[mt][ns][reg] + posb[m];
                tb[(long)m * HW + n0 + ns * 16 + lr] = f2h(v);
            }
}

// ---------------- merged conv3+conv5 via f16 dot2; 2 groups per block.
// LDS holds channel-PAIR packed u32 tiles (one plane per group).
// SRCF16: src is f16 ushort planes; else f32 planes.
template<bool SRCF16>
__global__ __launch_bounds__(256) void dualconv(
    const void* __restrict__ src_, int srcC,
    const unsigned* __restrict__ w3pk,  // [G][9] u32 f16-pairs
    const float* __restrict__ b3,
    const unsigned* __restrict__ w5pk,  // [G][25] u32 f16-pairs
    const float* __restrict__ b5,
    int s3, unsigned short* __restrict__ r3a, long st3a,
    unsigned short* __restrict__ r3b, long st3b,
    int s5, unsigned short* __restrict__ r5a, long st5a,
    unsigned short* __restrict__ r5b, long st5b)
{
    int gp = blockIdx.y, b = blockIdx.z, y0 = blockIdx.x * 8;
    __shared__ __align__(16) unsigned tile[2][12][132]; // [gi][row -2..9][col -2..129]
    int tid = threadIdx.x;
    int c0 = 4 * gp;
    const unsigned short* sH = (const unsigned short*)src_ + (long)b * srcC * HW;
    const float* sF = (const float*)src_ + (long)b * srcC * HW;
    const int TOT = 2 * 12 * 132;
    for (int idx = tid; idx < TOT; idx += 256) {
        int gi = idx / (12 * 132);
        int rem = idx - gi * (12 * 132);
        int r = rem / 132, ci = rem - r * 132;
        int row = y0 + r - 2, col = ci - 2;
        unsigned u = 0;
        if (row >= 0 && row < HH && col >= 0 && col < WW) {
            long off = (long)(c0 + 2 * gi) * HW + row * WW + col;
            if (SRCF16) {
                u = (unsigned)sH[off] | ((unsigned)sH[off + HW] << 16);
            } else {
                u = packh(sF[off], sF[off + HW]);
            }
        }
        tile[gi][r][ci] = u;
    }
    __syncthreads();
    int xq = tid & 31, yy = tid >> 5;
    int x0 = xq * 4;
    float a3[2][4], a5[2][4];
    #pragma unroll
    for (int gi = 0; gi < 2; ++gi) {
        int g = 2 * gp + gi;
        #pragma unroll
        for (int j = 0; j < 4; ++j) { a3[gi][j] = b3[g]; a5[gi][j] = b5[g]; }
        unsigned w5v[25], w3v[9];
        #pragma unroll
        for (int i = 0; i < 25; ++i) w5v[i] = w5pk[g * 25 + i];
        #pragma unroll
        for (int i = 0; i < 9; ++i) w3v[i] = w3pk[g * 9 + i];
        #pragma unroll
        for (int r = 0; r < 5; ++r) {
            const unsigned* p = &tile[gi][yy + r][x0];
            unsigned win[8];
            *(f32x4*)win = *(const f32x4*)p;
            *(f32x4*)(win + 4) = *(const f32x4*)(p + 4);
            #pragma unroll
            for (int dx = 0; dx < 5; ++dx)
                #pragma unroll
                for (int j = 0; j < 4; ++j)
                    a5[gi][j] = dot2acc(win[j + dx], w5v[r * 5 + dx], a5[gi][j]);
            if (r >= 1 && r <= 3) {
                #pragma unroll
                for (int dx = 0; dx < 3; ++dx)
                    #pragma unroll
                    for (int j = 0; j < 4; ++j)
                        a3[gi][j] = dot2acc(win[j + dx + 1], w3v[(r - 1) * 3 + dx], a3[gi][j]);
            }
        }
    }
    long prow = (long)(y0 + yy) * WW + x0;
    #pragma unroll
    for (int gi = 0; gi < 2; ++gi) {
        int g = 2 * gp + gi;
        us4 v3, v5;
        #pragma unroll
        for (int j = 0; j < 4; ++j) { v3[j] = f2bf(a3[gi][j]); v5[j] = f2bf(a5[gi][j]); }
        unsigned short* d3 = (g < s3) ? r3a + (long)b * st3a + (long)g * HW
                                      : r3b + (long)b * st3b + (long)(g - s3) * HW;
        unsigned short* d5 = (g < s5) ? r5a + (long)b * st5a + (long)g * HW
                                      : r5b + (long)b * st5b + (long)(g - s5) * HW;
        *(us4*)(d3 + prow) = v3;
        *(us4*)(d5 + prow) = v5;
    }
}

// ---------------- Gram + norms (bf16 in, MFMA)
__global__ __launch_bounds__(64) void gram_mfma(
    const unsigned short* __restrict__ q,  // [NB][128][HW]
    const unsigned short* __restrict__ k,
    float* __restrict__ gbuf)              // [NB*8][288]
{
    int bh = blockIdx.x, chunk = blockIdx.y;
    int b = bh >> 3, h = bh & 7;
    int l = threadIdx.x;
    int r = l & 15, koff = (l >> 4) * 8;
    const unsigned short* qrow = q + ((long)b * 128 + h * 16 + r) * HW;
    const unsigned short* krow = k + ((long)b * 128 + h * 16 + r) * HW;
    f32x4 acc = {0.f, 0.f, 0.f, 0.f};
    float sq = 0.f, sk = 0.f;
    int n0 = chunk * 512;
    for (int n = n0; n < n0 + 512; n += 32) {
        bf16x8 af = *(const bf16x8*)(qrow + n + koff);
        bf16x8 bf = *(const bf16x8*)(krow + n + koff);
        #pragma unroll
        for (int j = 0; j < 8; ++j) {
            float fq = bf2f((unsigned short)af[j]);
            float fk = bf2f((unsigned short)bf[j]);
            sq += fq * fq; sk += fk * fk;
        }
        acc = __builtin_amdgcn_mfma_f32_16x16x32_bf16(af, bf, acc, 0, 0, 0);
    }
    float* gb = gbuf + bh * 288;
    #pragma unroll
    for (int reg = 0; reg < 4; ++reg) {
        int row = (l >> 4) * 4 + reg;
        atomicAdd(&gb[row * 16 + r], acc[reg]);
    }
    sq += __shfl_xor(sq, 16); sq += __shfl_xor(sq, 32);
    sk += __shfl_xor(sk, 16); sk += __shfl_xor(sk, 32);
    if (l < 16) { atomicAdd(&gb[256 + r], sq); atomicAdd(&gb[272 + r], sk); }
}

// ---------------- softmax + fold into packed bf16 proj weights
__global__ __launch_bounds__(256) void attn_fold(
    const float* __restrict__ gbuf, const float* __restrict__ temp,
    const float* __restrict__ projw,     // [128][256]
    unsigned* __restrict__ wallpk)       // [NB][128][128] u32 bf16-pairs
{
    int bh = blockIdx.x;
    int b = bh >> 3, h = bh & 7;
    const float* gb = gbuf + bh * 288;
    __shared__ float logit[16][16];
    __shared__ float A[16][16];
    int tid = threadIdx.x;
    int d = tid >> 4, e = tid & 15;
    {
        float nq = fmaxf(sqrtf(gb[256 + d]), 1e-12f);
        float nk = fmaxf(sqrtf(gb[272 + e]), 1e-12f);
        logit[d][e] = gb[d * 16 + e] / (nq * nk) * temp[h];
    }
    __syncthreads();
    float m = -1e30f;
    #pragma unroll
    for (int j = 0; j < 16; ++j) m = fmaxf(m, logit[d][j]);
    float ex = expf(logit[d][e] - m);
    A[d][e] = ex;
    __syncthreads();
    float sum = 0.f;
    #pragma unroll
    for (int j = 0; j < 16; ++j) sum += A[d][j];
    __syncthreads();
    A[d][e] = ex / sum;
    __syncthreads();
    int ep = tid & 7, co0 = tid >> 3;
    for (int co = co0; co < 128; co += 32) {
        float lo = 0.f, hi = 0.f;
        #pragma unroll
        for (int dd = 0; dd < 16; ++dd) {
            float pw = projw[co * 256 + h * 16 + dd];
            lo += pw * A[dd][2 * ep];
            hi += pw * A[dd][2 * ep + 1];
        }
        wallpk[((long)b * 128 + co) * 128 + h * 8 + ep] = packbf(lo, hi);
    }
    if (h == 0) {
        for (int idx = tid; idx < 128 * 64; idx += 256) {
            int co = idx >> 6, cp = idx & 63;
            wallpk[((long)b * 128 + co) * 128 + 64 + cp] =
                packbf(projw[co * 256 + 128 + 2 * cp], projw[co * 256 + 129 + 2 * cp]);
        }
    }
}

// ---------------- K5b: out f32 = wallpk @ vy  (M=128, K=256, N=HW)
__global__ __launch_bounds__(256) void gemm_out(
    const unsigned* __restrict__ wpk,       // [NB][128][128] u32 (L2)
    const unsigned short* __restrict__ vy,  // [NB][256][HW] bf16
    float* __restrict__ out)                // [NB][128][HW]
{
    int b = blockIdx.z;
    int n0 = blockIdx.x * 32;
    const unsigned* wb = wpk + (long)b * 128 * 128;
    const unsigned short* vyb = vy + (long)b * 256 * HW;
    float* ob = out + (long)b * 128 * HW;
    __shared__ unsigned Bs[32][129];
    int tid = threadIdx.x;
    int oct = tid & 7, kpb = tid >> 3;
    #pragma unroll
    for (int p = 0; p < 4; ++p) {
        int kp = p * 32 + kpb;
        us4 lo = *(const us4*)(vyb + (long)(2 * kp) * HW + n0 + oct * 4);
        us4 hi = *(const us4*)(vyb + (long)(2 * kp + 1) * HW + n0 + oct * 4);
        #pragma unroll
        for (int j = 0; j < 4; ++j)
            Bs[oct * 4 + j][kp] = (unsigned)lo[j] | ((unsigned)hi[j] << 16);
    }
    __syncthreads();
    int w = tid >> 6, l = tid & 63;
    int lr = l & 15, lg = l >> 4;
    f32x4 acc[2][2] = {};
    #pragma unroll
    for (int kk = 0; kk < 8; ++kk) {
        bf16x8 af[2];
        #pragma unroll
        for (int i = 0; i < 2; ++i) {
            int m = (w * 2 + i) * 16 + lr;
            af[i] = *(const bf16x8*)(wb + (long)m * 128 + kk * 16 + lg * 4);
        }
        #pragma unroll
        for (int ns = 0; ns < 2; ++ns) {
            bf16x8 bf = *(const bf16x8*)(&Bs[ns * 16 + lr][kk * 16 + lg * 4]);
            #pragma unroll
            for (int i = 0; i < 2; ++i)
                acc[i][ns] = __builtin_amdgcn_mfma_f32_16x16x32_bf16(
                    af[i], bf, acc[i][ns], 0, 0, 0);
        }
    }
    #pragma unroll
    for (int i = 0; i < 2; ++i)
        #pragma unroll
        for (int ns = 0; ns < 2; ++ns)
            #pragma unroll
            for (int reg = 0; reg < 4; ++reg) {
                int m = (w * 2 + i) * 16 + lg * 4 + reg;
                ob[(long)m * HW + n0 + ns * 16 + lr] = acc[i][ns][reg];
            }
}

extern "C" void kernel_launch(void* const* d_in, const int* in_sizes, int n_in,
                              void* d_out, int out_size, void* d_ws, size_t ws_size,
                              hipStream_t stream) {
    const float* x      = (const float*)d_in[0];
    const float* pos_w  = (const float*)d_in[1];
    const float* pos_b  = (const float*)d_in[2];
    const float* qd3_w  = (const float*)d_in[3];
    const float* qd3_b  = (const float*)d_in[4];
    const float* qd5_w  = (const float*)d_in[5];
    const float* qd5_b  = (const float*)d_in[6];
    const float* temp   = (const float*)d_in[7];
    const float* d3_w   = (const float*)d_in[8];
    const float* d3_b   = (const float*)d_in[9];
    const float* d5_w   = (const float*)d_in[10];
    const float* d5_b   = (const float*)d_in[11];
    const float* proj_w = (const float*)d_in[12];
    float* out = (float*)d_out;

    size_t perb = 896UL * HW * 2 + 128UL * 128 * 4;
    size_t fixedb = 64UL * 288 * 4 + 384UL * 64 * 4 + 8704UL * 4;
    int NB = 8;
    while (NB > 1 && (size_t)NB * perb + fixedb > ws_size) NB >>= 1;

    char* base = (char*)d_ws;
    unsigned short* t  = (unsigned short*)base; base += (size_t)NB * 384 * HW * 2;
    unsigned short* qb = (unsigned short*)base; base += (size_t)NB * 128 * HW * 2;
    unsigned short* kb = (unsigned short*)base; base += (size_t)NB * 128 * HW * 2;
    unsigned short* vy = (unsigned short*)base; base += (size_t)NB * 256 * HW * 2;
    unsigned* wallpk   = (unsigned*)base;       base += (size_t)NB * 128 * 128 * 4;
    float* gram        = (float*)base;          base += 64UL * 288 * 4;
    unsigned* poswpk   = (unsigned*)base;       base += 384UL * 64 * 4;
    unsigned* cwpk     = (unsigned*)base;
    unsigned* qd3pk = cwpk;
    unsigned* qd5pk = cwpk + 192 * 9;
    unsigned* d3pk  = cwpk + 192 * 9 + 192 * 25;
    unsigned* d5pk  = cwpk + 192 * 9 + 192 * 25 + 64 * 9;

    packw<<<(384 * 64 + 255) / 256, 256, 0, stream>>>(pos_w, poswpk);
    packcw<<<(8704 + 255) / 256, 256, 0, stream>>>(qd3_w, qd5_w, d3_w, d5_w, cwpk);

    for (int b0 = 0; b0 < 8; b0 += NB) {
        const float* xb = x + (long)b0 * 128 * HW;
        float* outb = out + (long)b0 * 128 * HW;

        gemm_t<<<dim3(HW / 32, 1, NB), 256, 0, stream>>>(poswpk, xb, pos_b, t);

        // conv3 on t: g<128 -> q ; g>=128 -> k rows 0..63
        // conv5 on t: g<64 -> k rows 64..127 ; g>=64 -> vy rows 0..127
        dualconv<true><<<dim3(16, 96, NB), 256, 0, stream>>>(
            t, 384, qd3pk, qd3_b, qd5pk, qd5_b,
            128, qb, 128L * HW, kb, 128L * HW,
            64, kb + 64L * HW, 128L * HW, vy, 256L * HW);

        zerok<<<(64 * 288 + 255) / 256, 256, 0, stream>>>(gram, 64 * 288);
        gram_mfma<<<dim3(NB * 8, 32), 64, 0, stream>>>(qb, kb, gram);
        attn_fold<<<NB * 8, 256, 0, stream>>>(gram, temp, proj_w, wallpk);

        // conv3 on x -> vy rows 128..191 ; conv5 on x -> vy rows 192..255
        dualconv<false><<<dim3(16, 32, NB), 256, 0, stream>>>(
            xb, 128, d3pk, d3_b, d5pk, d5_b,
            64, vy + 128L * HW, 256L * HW, vy + 128L * HW, 256L * HW,
            64, vy + 192L * HW, 256L * HW, vy + 192L * HW, 256L * HW);

        gemm_out<<<dim3(HW / 32, 1, NB), 256, 0, stream>>>(wallpk, vy, outb);
    }
}

// Round 6
// 238.351 us; speedup vs baseline: 4.2361x; 1.1771x over previous
//
#include <hip/hip_runtime.h>
#include <hip/hip_bf16.h>

// ---------------------------------------------------------------------------
// B=8, C=128, H=W=128, hw=16384, heads=8.
//  packx: x f32 -> xpk u32 (f16 channel-pairs)        [once per chunk]
//  packw/packcw: weights -> f16-pair packed           [once]
//  K1 gemm_t:  tpk u32 = f16-pair-packed (pos_w @ x + pos_b)   (MFMA f16)
//  K2 dualconv(xpk): conv3+conv5 on x -> vy rows 128..255      (v_dot2 f16)
//  K3 dualconv(tpk): conv3+conv5 on t -> q(alias xpk),k,v bf16
//  K4 gram: S[16][16], |q|^2,|k|^2 per (b,h)                   (MFMA bf16)
//  K5 attn_fold: softmax fold -> wallpk (bf16 pairs)
//  K6 gemm_out: out f32 = wallpk @ vy                          (MFMA bf16)
// ---------------------------------------------------------------------------

#define HW 16384
#define HH 128
#define WW 128

typedef __attribute__((ext_vector_type(8))) short bf16x8;
typedef __attribute__((ext_vector_type(8))) _Float16 f16x8;
typedef __attribute__((ext_vector_type(4))) float f32x4;
typedef __attribute__((ext_vector_type(4))) unsigned short us4;
typedef _Float16 half2t __attribute__((ext_vector_type(2)));

__device__ inline unsigned short f2bf(float f) {
    unsigned u = __float_as_uint(f);
    return (unsigned short)((u + 0x7FFFu + ((u >> 16) & 1u)) >> 16);
}
__device__ inline float bf2f(unsigned short us) {
    return __uint_as_float(((unsigned)us) << 16);
}
__device__ inline unsigned packbf(float lo, float hi) {
    return (unsigned)f2bf(lo) | ((unsigned)f2bf(hi) << 16);
}
__device__ inline unsigned short f2h(float f) {
    _Float16 h = (_Float16)f;
    return __builtin_bit_cast(unsigned short, h);
}
__device__ inline unsigned packh(float lo, float hi) {
    return (unsigned)f2h(lo) | ((unsigned)f2h(hi) << 16);
}

#if defined(__has_builtin)
#if __has_builtin(__builtin_amdgcn_fdot2)
#define HAVE_FDOT2 1
#endif
#endif

__device__ inline float dot2acc(unsigned a, unsigned b, float c) {
#ifdef HAVE_FDOT2
    return __builtin_amdgcn_fdot2(__builtin_bit_cast(half2t, a),
                                  __builtin_bit_cast(half2t, b), c, false);
#else
    half2t ha = __builtin_bit_cast(half2t, a);
    half2t hb = __builtin_bit_cast(half2t, b);
    return c + (float)ha[0] * (float)hb[0] + (float)ha[1] * (float)hb[1];
#endif
}

__global__ void zerok(float* p, int n) {
    int i = blockIdx.x * 256 + threadIdx.x;
    if (i < n) p[i] = 0.f;
}

// x [NB][128][HW] f32 -> xpk [NB][64][HW] u32 f16-channel-pairs
__global__ __launch_bounds__(256) void packx(const float* __restrict__ x,
                                             unsigned* __restrict__ xpk, int nb) {
    long id = (long)blockIdx.x * 256 + threadIdx.x;   // over nb*64*(HW/4)
    if (id >= (long)nb * 64 * (HW / 4)) return;
    int n4 = (int)(id % (HW / 4));
    long rest = id / (HW / 4);
    int p = (int)(rest & 63);
    int b = (int)(rest >> 6);
    const float* r0 = x + ((long)b * 128 + 2 * p) * HW + n4 * 4;
    float4 a = *(const float4*)r0;
    float4 c = *(const float4*)(r0 + HW);
    uint4 o;
    o.x = packh(a.x, c.x); o.y = packh(a.y, c.y);
    o.z = packh(a.z, c.z); o.w = packh(a.w, c.w);
    *(uint4*)(xpk + ((long)b * 64 + p) * HW + n4 * 4) = o;
}

// pack pos_w [384][128] f32 -> poswpk [384][64] u32 (f16 pairs along k)
__global__ __launch_bounds__(256) void packw(const float* __restrict__ w,
                                             unsigned* __restrict__ wpk) {
    int id = blockIdx.x * 256 + threadIdx.x;   // 384*64
    if (id >= 384 * 64) return;
    int m = id >> 6, kp = id & 63;
    wpk[id] = packh(w[m * 128 + 2 * kp], w[m * 128 + 2 * kp + 1]);
}

// pack conv weights: channel-pair f16 per tap.
__global__ __launch_bounds__(256) void packcw(
    const float* __restrict__ qd3, const float* __restrict__ qd5,
    const float* __restrict__ d3, const float* __restrict__ d5,
    unsigned* __restrict__ o) {
    int id = blockIdx.x * 256 + threadIdx.x;
    if (id < 192 * 9) {
        int g = id / 9, tp = id % 9;
        o[id] = packh(qd3[(g * 2) * 9 + tp], qd3[(g * 2 + 1) * 9 + tp]);
    } else if (id < 192 * 9 + 192 * 25) {
        int r = id - 192 * 9; int g = r / 25, tp = r % 25;
        o[id] = packh(qd5[(g * 2) * 25 + tp], qd5[(g * 2 + 1) * 25 + tp]);
    } else if (id < 192 * 9 + 192 * 25 + 64 * 9) {
        int r = id - 192 * 9 - 192 * 25; int g = r / 9, tp = r % 9;
        o[id] = packh(d3[(g * 2) * 9 + tp], d3[(g * 2 + 1) * 9 + tp]);
    } else if (id < 192 * 9 + 192 * 25 + 64 * 9 + 64 * 25) {
        int r = id - 192 * 9 - 192 * 25 - 64 * 9; int g = r / 25, tp = r % 25;
        o[id] = packh(d5[(g * 2) * 25 + tp], d5[(g * 2 + 1) * 25 + tp]);
    }
}

// ---------------- K1: tpk = f16-pair-packed(pos_w @ x + b)  (M=384,K=128,N=HW)
__global__ __launch_bounds__(256) void gemm_t(
    const unsigned* __restrict__ wpk,   // [384][64] u32 f16 k-pairs (L2)
    const unsigned* __restrict__ xpk,   // [NB][64][HW] u32 f16 ch-pairs
    const float* __restrict__ posb,     // [384]
    unsigned* __restrict__ tpk)         // [NB][192][HW] u32 f16 ch-pairs
{
    int b = blockIdx.z;
    int n0 = blockIdx.x * 64;
    const unsigned* xb = xpk + (long)b * 64 * HW;
    unsigned* tb = tpk + (long)b * 192 * HW;
    __shared__ unsigned Bs[64][65];     // [n][kp]
    int tid = threadIdx.x;
    {   // fill 64 kp-rows x 64 n, transposing to [n][kp]
        int kp = tid >> 2, nq = tid & 3;
        const unsigned* src = xb + (long)kp * HW + n0 + nq * 16;
        uint4 v0 = *(const uint4*)(src);
        uint4 v1 = *(const uint4*)(src + 4);
        uint4 v2 = *(const uint4*)(src + 8);
        uint4 v3 = *(const uint4*)(src + 12);
        int nb_ = nq * 16;
        Bs[nb_ + 0][kp] = v0.x;  Bs[nb_ + 1][kp] = v0.y;
        Bs[nb_ + 2][kp] = v0.z;  Bs[nb_ + 3][kp] = v0.w;
        Bs[nb_ + 4][kp] = v1.x;  Bs[nb_ + 5][kp] = v1.y;
        Bs[nb_ + 6][kp] = v1.z;  Bs[nb_ + 7][kp] = v1.w;
        Bs[nb_ + 8][kp] = v2.x;  Bs[nb_ + 9][kp] = v2.y;
        Bs[nb_ + 10][kp] = v2.z; Bs[nb_ + 11][kp] = v2.w;
        Bs[nb_ + 12][kp] = v3.x; Bs[nb_ + 13][kp] = v3.y;
        Bs[nb_ + 14][kp] = v3.z; Bs[nb_ + 15][kp] = v3.w;
    }
    __syncthreads();
    int w = tid >> 6, l = tid & 63;
    int lr = l & 15, lg = l >> 4;
    f32x4 acc[6][4] = {};
    #pragma unroll
    for (int kk = 0; kk < 4; ++kk) {
        f16x8 af[6];
        #pragma unroll
        for (int mt = 0; mt < 6; ++mt) {
            int m = (w * 6 + mt) * 16 + lr;
            af[mt] = *(const f16x8*)(wpk + (long)m * 64 + kk * 16 + lg * 4);
        }
        #pragma unroll
        for (int ns = 0; ns < 4; ++ns) {
            f16x8 bf = *(const f16x8*)(&Bs[ns * 16 + lr][kk * 16 + lg * 4]);
            #pragma unroll
            for (int mt = 0; mt < 6; ++mt)
                acc[mt][ns] = __builtin_amdgcn_mfma_f32_16x16x32_f16(
                    af[mt], bf, acc[mt][ns], 0, 0, 0);
        }
    }
    #pragma unroll
    for (int mt = 0; mt < 6; ++mt) {
        int m0 = w * 96 + mt * 16 + lg * 4;
        float b0v = posb[m0], b1v = posb[m0 + 1], b2v = posb[m0 + 2], b3v = posb[m0 + 3];
        int p0 = m0 >> 1;
        #pragma unroll
        for (int ns = 0; ns < 4; ++ns) {
            int col = n0 + ns * 16 + lr;
            tb[(long)p0 * HW + col]       = packh(acc[mt][ns][0] + b0v, acc[mt][ns][1] + b1v);
            tb[(long)(p0 + 1) * HW + col] = packh(acc[mt][ns][2] + b2v, acc[mt][ns][3] + b3v);
        }
    }
}

// ---------------- merged conv3+conv5 via f16 dot2; src is u32 pair-packed.
__global__ __launch_bounds__(256) void dualconv(
    const unsigned* __restrict__ src, int srcP,   // [NB][srcP][HW] u32
    const unsigned* __restrict__ w3pk, const float* __restrict__ b3,
    const unsigned* __restrict__ w5pk, const float* __restrict__ b5,
    int s3, unsigned short* __restrict__ r3a, long st3a,
    unsigned short* __restrict__ r3b, long st3b,
    int s5, unsigned short* __restrict__ r5a, long st5a,
    unsigned short* __restrict__ r5b, long st5b)
{
    int gp = blockIdx.y, b = blockIdx.z, y0 = blockIdx.x * 8;
    __shared__ __align__(16) unsigned tile[2][12][132];
    int tid = threadIdx.x;
    const unsigned* sb = src + ((long)b * srcP + 2 * gp) * HW;
    const int TOT = 2 * 12 * 132;
    for (int idx = tid; idx < TOT; idx += 256) {
        int gi = idx / (12 * 132);
        int rem = idx - gi * (12 * 132);
        int r = rem / 132, ci = rem - r * 132;
        int row = y0 + r - 2, col = ci - 2;
        unsigned u = 0;
        if (row >= 0 && row < HH && col >= 0 && col < WW)
            u = sb[(long)gi * HW + row * WW + col];
        tile[gi][r][ci] = u;
    }
    __syncthreads();
    int xq = tid & 31, yy = tid >> 5;
    int x0 = xq * 4;
    float a3[2][4], a5[2][4];
    #pragma unroll
    for (int gi = 0; gi < 2; ++gi) {
        int g = 2 * gp + gi;
        #pragma unroll
        for (int j = 0; j < 4; ++j) { a3[gi][j] = b3[g]; a5[gi][j] = b5[g]; }
        unsigned w5v[25], w3v[9];
        #pragma unroll
        for (int i = 0; i < 25; ++i) w5v[i] = w5pk[g * 25 + i];
        #pragma unroll
        for (int i = 0; i < 9; ++i) w3v[i] = w3pk[g * 9 + i];
        #pragma unroll
        for (int r = 0; r < 5; ++r) {
            const unsigned* p = &tile[gi][yy + r][x0];
            unsigned win[8];
            *(f32x4*)win = *(const f32x4*)p;
            *(f32x4*)(win + 4) = *(const f32x4*)(p + 4);
            #pragma unroll
            for (int dx = 0; dx < 5; ++dx)
                #pragma unroll
                for (int j = 0; j < 4; ++j)
                    a5[gi][j] = dot2acc(win[j + dx], w5v[r * 5 + dx], a5[gi][j]);
            if (r >= 1 && r <= 3) {
                #pragma unroll
                for (int dx = 0; dx < 3; ++dx)
                    #pragma unroll
                    for (int j = 0; j < 4; ++j)
                        a3[gi][j] = dot2acc(win[j + dx + 1], w3v[(r - 1) * 3 + dx], a3[gi][j]);
            }
        }
    }
    long prow = (long)(y0 + yy) * WW + x0;
    #pragma unroll
    for (int gi = 0; gi < 2; ++gi) {
        int g = 2 * gp + gi;
        us4 v3, v5;
        #pragma unroll
        for (int j = 0; j < 4; ++j) { v3[j] = f2bf(a3[gi][j]); v5[j] = f2bf(a5[gi][j]); }
        unsigned short* d3 = (g < s3) ? r3a + (long)b * st3a + (long)g * HW
                                      : r3b + (long)b * st3b + (long)(g - s3) * HW;
        unsigned short* d5 = (g < s5) ? r5a + (long)b * st5a + (long)g * HW
                                      : r5b + (long)b * st5b + (long)(g - s5) * HW;
        *(us4*)(d3 + prow) = v3;
        *(us4*)(d5 + prow) = v5;
    }
}

// ---------------- Gram + norms (bf16 in, MFMA)
__global__ __launch_bounds__(64) void gram_mfma(
    const unsigned short* __restrict__ q,  // [NB][128][HW]
    const unsigned short* __restrict__ k,
    float* __restrict__ gbuf)              // [NB*8][288]
{
    int bh = blockIdx.x, chunk = blockIdx.y;
    int b = bh >> 3, h = bh & 7;
    int l = threadIdx.x;
    int r = l & 15, koff = (l >> 4) * 8;
    const unsigned short* qrow = q + ((long)b * 128 + h * 16 + r) * HW;
    const unsigned short* krow = k + ((long)b * 128 + h * 16 + r) * HW;
    f32x4 acc = {0.f, 0.f, 0.f, 0.f};
    float sq = 0.f, sk = 0.f;
    int n0 = chunk * 512;
    for (int n = n0; n < n0 + 512; n += 32) {
        bf16x8 af = *(const bf16x8*)(qrow + n + koff);
        bf16x8 bf = *(const bf16x8*)(krow + n + koff);
        #pragma unroll
        for (int j = 0; j < 8; ++j) {
            float fq = bf2f((unsigned short)af[j]);
            float fk = bf2f((unsigned short)bf[j]);
            sq += fq * fq; sk += fk * fk;
        }
        acc = __builtin_amdgcn_mfma_f32_16x16x32_bf16(af, bf, acc, 0, 0, 0);
    }
    float* gb = gbuf + bh * 288;
    #pragma unroll
    for (int reg = 0; reg < 4; ++reg) {
        int row = (l >> 4) * 4 + reg;
        atomicAdd(&gb[row * 16 + r], acc[reg]);
    }
    sq += __shfl_xor(sq, 16); sq += __shfl_xor(sq, 32);
    sk += __shfl_xor(sk, 16); sk += __shfl_xor(sk, 32);
    if (l < 16) { atomicAdd(&gb[256 + r], sq); atomicAdd(&gb[272 + r], sk); }
}

// ---------------- softmax + fold into packed bf16 proj weights
__global__ __launch_bounds__(256) void attn_fold(
    const float* __restrict__ gbuf, const float* __restrict__ temp,
    const float* __restrict__ projw,     // [128][256]
    unsigned* __restrict__ wallpk)       // [NB][128][128] u32 bf16-pairs
{
    int bh = blockIdx.x;
    int b = bh >> 3, h = bh & 7;
    const float* gb = gbuf + bh * 288;
    __shared__ float logit[16][16];
    __shared__ float A[16][16];
    int tid = threadIdx.x;
    int d = tid >> 4, e = tid & 15;
    {
        float nq = fmaxf(sqrtf(gb[256 + d]), 1e-12f);
        float nk = fmaxf(sqrtf(gb[272 + e]), 1e-12f);
        logit[d][e] = gb[d * 16 + e] / (nq * nk) * temp[h];
    }
    __syncthreads();
    float m = -1e30f;
    #pragma unroll
    for (int j = 0; j < 16; ++j) m = fmaxf(m, logit[d][j]);
    float ex = expf(logit[d][e] - m);
    A[d][e] = ex;
    __syncthreads();
    float sum = 0.f;
    #pragma unroll
    for (int j = 0; j < 16; ++j) sum += A[d][j];
    __syncthreads();
    A[d][e] = ex / sum;
    __syncthreads();
    int ep = tid & 7, co0 = tid >> 3;
    for (int co = co0; co < 128; co += 32) {
        float lo = 0.f, hi = 0.f;
        #pragma unroll
        for (int dd = 0; dd < 16; ++dd) {
            float pw = projw[co * 256 + h * 16 + dd];
            lo += pw * A[dd][2 * ep];
            hi += pw * A[dd][2 * ep + 1];
        }
        wallpk[((long)b * 128 + co) * 128 + h * 8 + ep] = packbf(lo, hi);
    }
    if (h == 0) {
        for (int idx = tid; idx < 128 * 64; idx += 256) {
            int co = idx >> 6, cp = idx & 63;
            wallpk[((long)b * 128 + co) * 128 + 64 + cp] =
                packbf(projw[co * 256 + 128 + 2 * cp], projw[co * 256 + 129 + 2 * cp]);
        }
    }
}

// ---------------- K6: out f32 = wallpk @ vy  (M=128, K=256, N=HW)
__global__ __launch_bounds__(256) void gemm_out(
    const unsigned* __restrict__ wpk,       // [NB][128][128] u32 (L2)
    const unsigned short* __restrict__ vy,  // [NB][256][HW] bf16
    float* __restrict__ out)                // [NB][128][HW]
{
    int b = blockIdx.z;
    int n0 = blockIdx.x * 32;
    const unsigned* wb = wpk + (long)b * 128 * 128;
    const unsigned short* vyb = vy + (long)b * 256 * HW;
    float* ob = out + (long)b * 128 * HW;
    __shared__ unsigned Bs[32][129];
    int tid = threadIdx.x;
    int oct = tid & 7, kpb = tid >> 3;
    #pragma unroll
    for (int p = 0; p < 4; ++p) {
        int kp = p * 32 + kpb;
        us4 lo = *(const us4*)(vyb + (long)(2 * kp) * HW + n0 + oct * 4);
        us4 hi = *(const us4*)(vyb + (long)(2 * kp + 1) * HW + n0 + oct * 4);
        #pragma unroll
        for (int j = 0; j < 4; ++j)
            Bs[oct * 4 + j][kp] = (unsigned)lo[j] | ((unsigned)hi[j] << 16);
    }
    __syncthreads();
    int w = tid >> 6, l = tid & 63;
    int lr = l & 15, lg = l >> 4;
    f32x4 acc[2][2] = {};
    #pragma unroll
    for (int kk = 0; kk < 8; ++kk) {
        bf16x8 af[2];
        #pragma unroll
        for (int i = 0; i < 2; ++i) {
            int m = (w * 2 + i) * 16 + lr;
            af[i] = *(const bf16x8*)(wb + (long)m * 128 + kk * 16 + lg * 4);
        }
        #pragma unroll
        for (int ns = 0; ns < 2; ++ns) {
            bf16x8 bf = *(const bf16x8*)(&Bs[ns * 16 + lr][kk * 16 + lg * 4]);
            #pragma unroll
            for (int i = 0; i < 2; ++i)
                acc[i][ns] = __builtin_amdgcn_mfma_f32_16x16x32_bf16(
                    af[i], bf, acc[i][ns], 0, 0, 0);
        }
    }
    #pragma unroll
    for (int i = 0; i < 2; ++i)
        #pragma unroll
        for (int ns = 0; ns < 2; ++ns)
            #pragma unroll
            for (int reg = 0; reg < 4; ++reg) {
                int m = (w * 2 + i) * 16 + lg * 4 + reg;
                ob[(long)m * HW + n0 + ns * 16 + lr] = acc[i][ns][reg];
            }
}

extern "C" void kernel_launch(void* const* d_in, const int* in_sizes, int n_in,
                              void* d_out, int out_size, void* d_ws, size_t ws_size,
                              hipStream_t stream) {
    const float* x      = (const float*)d_in[0];
    const float* pos_w  = (const float*)d_in[1];
    const float* pos_b  = (const float*)d_in[2];
    const float* qd3_w  = (const float*)d_in[3];
    const float* qd3_b  = (const float*)d_in[4];
    const float* qd5_w  = (const float*)d_in[5];
    const float* qd5_b  = (const float*)d_in[6];
    const float* temp   = (const float*)d_in[7];
    const float* d3_w   = (const float*)d_in[8];
    const float* d3_b   = (const float*)d_in[9];
    const float* d5_w   = (const float*)d_in[10];
    const float* d5_b   = (const float*)d_in[11];
    const float* proj_w = (const float*)d_in[12];
    float* out = (float*)d_out;

    // per-batch: tpk 12.58MB + A(xpk|qb) 4.19 + kb 4.19 + vy 8.39 + wallpk 64K
    size_t perb = (size_t)HW * 1792 + 65536;
    size_t fixedb = 64UL * 288 * 4 + 384UL * 64 * 4 + 8704UL * 4;
    int NB = 8;
    while (NB > 1 && (size_t)NB * perb + fixedb > ws_size) NB >>= 1;

    char* base = (char*)d_ws;
    unsigned* tpk      = (unsigned*)base;       base += (size_t)NB * 192 * HW * 4;
    unsigned* xpk      = (unsigned*)base;                      // aliased region A
    unsigned short* qb = (unsigned short*)base; base += (size_t)NB * 128 * HW * 2;
    unsigned short* kb = (unsigned short*)base; base += (size_t)NB * 128 * HW * 2;
    unsigned short* vy = (unsigned short*)base; base += (size_t)NB * 256 * HW * 2;
    unsigned* wallpk   = (unsigned*)base;       base += (size_t)NB * 128 * 128 * 4;
    float* gram        = (float*)base;          base += 64UL * 288 * 4;
    unsigned* poswpk   = (unsigned*)base;       base += 384UL * 64 * 4;
    unsigned* cwpk     = (unsigned*)base;
    unsigned* qd3pk = cwpk;
    unsigned* qd5pk = cwpk + 192 * 9;
    unsigned* d3pk  = cwpk + 192 * 9 + 192 * 25;
    unsigned* d5pk  = cwpk + 192 * 9 + 192 * 25 + 64 * 9;

    packw<<<(384 * 64 + 255) / 256, 256, 0, stream>>>(pos_w, poswpk);
    packcw<<<(8704 + 255) / 256, 256, 0, stream>>>(qd3_w, qd5_w, d3_w, d5_w, cwpk);

    for (int b0 = 0; b0 < 8; b0 += NB) {
        const float* xb = x + (long)b0 * 128 * HW;
        float* outb = out + (long)b0 * 128 * HW;

        // x -> f16 channel-pair packed
        packx<<<NB * 1024, 256, 0, stream>>>(xb, xpk, NB);

        // t (pair-packed) = pos_w @ x + b
        gemm_t<<<dim3(HW / 64, 1, NB), 256, 0, stream>>>(poswpk, xpk, pos_b, tpk);

        // convs on x FIRST (xpk dies here; region A becomes qb after)
        // conv3 -> vy rows 128..191 ; conv5 -> vy rows 192..255
        dualconv<<<dim3(16, 32, NB), 256, 0, stream>>>(
            xpk, 64, d3pk, d3_b, d5pk, d5_b,
            64, vy + 128L * HW, 256L * HW, vy + 128L * HW, 256L * HW,
            64, vy + 192L * HW, 256L * HW, vy + 192L * HW, 256L * HW);

        // convs on t: conv3: g<128 -> q ; g>=128 -> k rows 0..63
        //             conv5: g<64 -> k rows 64..127 ; g>=64 -> vy rows 0..127
        dualconv<<<dim3(16, 96, NB), 256, 0, stream>>>(
            tpk, 192, qd3pk, qd3_b, qd5pk, qd5_b,
            128, qb, 128L * HW, kb, 128L * HW,
            64, kb + 64L * HW, 128L * HW, vy, 256L * HW);

        zerok<<<(64 * 288 + 255) / 256, 256, 0, stream>>>(gram, 64 * 288);
        gram_mfma<<<dim3(NB * 8, 32), 64, 0, stream>>>(qb, kb, gram);
        attn_fold<<<NB * 8, 256, 0, stream>>>(gram, temp, proj_w, wallpk);

        gemm_out<<<dim3(HW / 32, 1, NB), 256, 0, stream>>>(wallpk, vy, outb);
    }
}